// Round 6
// baseline (335.749 us; speedup 1.0000x reference)
//
#include <hip/hip_runtime.h>
#include <math.h>

#define BATCH  2
#define NVOX   8000
#define MT     32            // queries per attn block
#define KT     64            // keys per tile
#define NTILES 125
#define QTILES 250
#define LOG2E  1.44269504f
#define MSTAT  32.0f         // static softmax shift (log2 domain)

typedef float  f32x16 __attribute__((ext_vector_type(16)));
typedef __bf16 bf16x8 __attribute__((ext_vector_type(8)));
typedef unsigned short u16x8 __attribute__((ext_vector_type(8)));

__device__ __forceinline__ unsigned short f2bf(float f) {
    return __builtin_bit_cast(unsigned short, (__bf16)f);
}
__device__ __forceinline__ unsigned int packbf(float lo, float hi) {
    return (unsigned int)f2bf(lo) | ((unsigned int)f2bf(hi) << 16);
}
// 2^x via v_exp_f32; s_nop covers the trans->VALU wait state.
__device__ __forceinline__ float fexp2(float x) {
    float r;
    asm("v_exp_f32 %0, %1\n\ts_nop 0" : "=v"(r) : "v"(x));
    return r;
}

// ---------------------------------------------------------------------------
// Kernel 1: projection GEMM. 1000 blocks x 192 thr, 16 voxels per block
// (~12 waves/CU for latency hiding). W fragments converted in-kernel from
// fp32 (L2-broadcast), LOG2E folded into q rows. Epilogue transposes through
// LDS so every global store is a coalesced 16B write.
//   qws [vox][16] bf16 hi|lo (log2e-scaled), kws [vox][8] bf16,
//   vws planar [b][c][n] bf16.
// ---------------------------------------------------------------------------
__global__ __launch_bounds__(192) void qkv_kernel(
    const float* __restrict__ x,
    const float* __restrict__ wq, const float* __restrict__ bq,
    const float* __restrict__ wk, const float* __restrict__ bk,
    const float* __restrict__ wv, const float* __restrict__ bv,
    unsigned short* __restrict__ qws, unsigned short* __restrict__ kws,
    unsigned short* __restrict__ vws)
{
    __shared__ __align__(16) unsigned short st[88 * 24];  // rows: 0-7 q-hi, 8-15 k, 16-79 v, 80-87 q-lo
    const int t = threadIdx.x, lane = t & 63, ot = t >> 6;
    const int l31 = lane & 31, h = lane >> 5;
    const int blk = blockIdx.x, b = blk / 500, v0 = (blk % 500) * 16;
    const int nL = v0 + (l31 & 15);               // clamp-free: duplicate cols 16-31

    // ---- W A-frags: lane owns o-row ot*32+l31, cols cc*16+8h+0..7 ----
    const int o = ot * 32 + l31;
    const float* wsrc;
    float scale = 1.0f;
    if (o < 8)       { wsrc = wq + o * 64; scale = LOG2E; }
    else if (o < 16) { wsrc = wk + (o - 8) * 64; }
    else             { wsrc = wv + ((o - 16) & 63) * 64; }   // o>=80 rows: junk, never stored

    bf16x8 Ah[4], Al[4];
#pragma unroll
    for (int cc = 0; cc < 4; ++cc) {
        float4 w0 = *(const float4*)(wsrc + cc * 16 + 8 * h);
        float4 w1 = *(const float4*)(wsrc + cc * 16 + 8 * h + 4);
        float wf[8] = { w0.x, w0.y, w0.z, w0.w, w1.x, w1.y, w1.z, w1.w };
        unsigned short hh[8], ll[8];
#pragma unroll
        for (int j = 0; j < 8; ++j) {
            float wv_ = wf[j] * scale;
            __bf16 hb = (__bf16)wv_;
            hh[j] = __builtin_bit_cast(unsigned short, hb);
            ll[j] = f2bf(wv_ - (float)hb);
        }
        Ah[cc] = __builtin_bit_cast(bf16x8, *(u16x8*)hh);
        Al[cc] = __builtin_bit_cast(bf16x8, *(u16x8*)ll);
    }

    // ---- X B-frags (hi/lo split) ----
    bf16x8 Bhi[4], Blo[4];
    const float* xb = x + (size_t)b * 64 * NVOX + nL;
#pragma unroll
    for (int cc = 0; cc < 4; ++cc) {
        unsigned short bh[8], bl[8];
#pragma unroll
        for (int j = 0; j < 8; ++j) {
            float xf = xb[(size_t)(cc * 16 + 8 * h + j) * NVOX];
            __bf16 xh = (__bf16)xf;
            bh[j] = __builtin_bit_cast(unsigned short, xh);
            bl[j] = f2bf(xf - (float)xh);
        }
        Bhi[cc] = __builtin_bit_cast(bf16x8, *(u16x8*)bh);
        Blo[cc] = __builtin_bit_cast(bf16x8, *(u16x8*)bl);
    }

    f32x16 acc;
#pragma unroll
    for (int r = 0; r < 16; ++r) acc[r] = 0.0f;
#pragma unroll
    for (int cc = 0; cc < 4; ++cc) {
        acc = __builtin_amdgcn_mfma_f32_32x32x16_bf16(Ah[cc], Bhi[cc], acc, 0, 0, 0);
        acc = __builtin_amdgcn_mfma_f32_32x32x16_bf16(Al[cc], Bhi[cc], acc, 0, 0, 0);
        acc = __builtin_amdgcn_mfma_f32_32x32x16_bf16(Ah[cc], Blo[cc], acc, 0, 0, 0);
    }

    // ---- stage results to LDS (cols 0-15 valid) ----
    if (l31 < 16) {
#pragma unroll
        for (int r = 0; r < 16; ++r) {
            int oo = ot * 32 + (r & 3) + 8 * (r >> 2) + 4 * h;
            if (oo >= 80) continue;
            float bias = (oo < 8) ? bq[oo] * LOG2E : (oo < 16) ? bk[oo - 8] : bv[oo - 16];
            float v = acc[r] + bias;
            if (oo < 8) {
                __bf16 hb = (__bf16)v;
                st[oo * 24 + l31]        = __builtin_bit_cast(unsigned short, hb);
                st[(80 + oo) * 24 + l31] = f2bf(v - (float)hb);
            } else {
                st[oo * 24 + l31] = f2bf(v);
            }
        }
    }
    __syncthreads();

    // ---- coalesced 16B stores from LDS ----
    if (t < 128) {                       // vws: 64 ch x 2 chunks of 8 vox
        int ch = t >> 1, part = t & 1;
        uint4 d = *(const uint4*)&st[(16 + ch) * 24 + part * 8];
        *(uint4*)(vws + ((size_t)b * 64 + ch) * NVOX + v0 + part * 8) = d;
    } else if (t < 160) {                // qws: 16 vox x {hi,lo} halves
        int i = t - 128, vox = i >> 1, half = i & 1;
        int rbase = half ? 80 : 0;
        unsigned short g[8];
#pragma unroll
        for (int r = 0; r < 8; ++r) g[r] = st[(rbase + r) * 24 + vox];
        *(uint4*)(qws + (size_t)(b * NVOX + v0 + vox) * 16 + half * 8) = *(uint4*)g;
    } else if (t < 176) {                // kws: 16 vox
        int vox = t - 160;
        unsigned short g[8];
#pragma unroll
        for (int r = 0; r < 8; ++r) g[r] = st[(8 + r) * 24 + vox];
        *(uint4*)(kws + (size_t)(b * NVOX + v0 + vox) * 8) = *(uint4*)g;
    }
}

// ---------------------------------------------------------------------------
// Kernel 2: flash attention, static-m softmax, zero main-loop barriers/LDS.
//   500 blocks x 512 thr (8 waves). Wave w owns tiles T = w+8S.
//   K AND V fragments double-buffered one tile ahead (true prefetch).
//   P transpose C-layout -> B-frag in-register (shfl_xor 32 + select).
// ---------------------------------------------------------------------------
__global__ __launch_bounds__(512, 4) void attn_kernel(
    const unsigned short* __restrict__ qws, const unsigned short* __restrict__ kws,
    const unsigned short* __restrict__ vws, const float* __restrict__ x,
    const float* __restrict__ gamma, float* __restrict__ out)
{
    __shared__ float smem_f[8704];          // 32KB merge + 2KB l
    float* l_sh = smem_f + 8192;            // [8][64]

    const int blk = blockIdx.x, b = blk / QTILES, m0 = (blk % QTILES) * MT;
    const int t = threadIdx.x, lane = t & 63, w = t >> 6;
    const int l31 = lane & 31, h = lane >> 5;

    // Q B-frag (log2e pre-folded): col=query l31, h=0 hi / h=1 lo
    const bf16x8 qf = __builtin_bit_cast(bf16x8,
        *(const u16x8*)(qws + (size_t)(b * NVOX + m0 + l31) * 16 + h * 8));

    const unsigned short* ksrc = kws + (size_t)b * NVOX * 8;
    const unsigned short* vb0  = vws + ((size_t)b * 64 + l31) * NVOX + 8 * h;
    const unsigned short* vb1  = vb0 + (size_t)32 * NVOX;

    f32x16 acc0, acc1, zro;
#pragma unroll
    for (int r = 0; r < 16; ++r) { acc0[r] = 0.0f; acc1[r] = 0.0f; zro[r] = 0.0f; }
    float sA = 0.0f, sB = 0.0f, sC = 0.0f, sD = 0.0f;

    // preload tile T = w (always < NTILES since w < 8)
    uint4 va0c[4], va1c[4];
    bf16x8 kf0c, kf1c;
    {
        const int n0 = w * KT;
#pragma unroll
        for (int s2 = 0; s2 < 4; ++s2) {
            va0c[s2] = *(const uint4*)(vb0 + n0 + 16 * s2);
            va1c[s2] = *(const uint4*)(vb1 + n0 + 16 * s2);
        }
        kf0c = __builtin_bit_cast(bf16x8, *(const u16x8*)(ksrc + (size_t)(n0 + l31) * 8));
        kf1c = __builtin_bit_cast(bf16x8, *(const u16x8*)(ksrc + (size_t)(n0 + 32 + l31) * 8));
    }

#pragma unroll 2
    for (int S = 0; S < 16; ++S) {
        const int T = w + 8 * S;
        if (T < NTILES) {
            const int Tn = T + 8;
            const bool pre = Tn < NTILES;

            // ---- issue next tile's loads FIRST (full tile of compute covers them)
            uint4 va0n[4], va1n[4];
            bf16x8 kf0n, kf1n;
            if (pre) {
                const int nn = Tn * KT;
#pragma unroll
                for (int s2 = 0; s2 < 4; ++s2) {
                    va0n[s2] = *(const uint4*)(vb0 + nn + 16 * s2);
                    va1n[s2] = *(const uint4*)(vb1 + nn + 16 * s2);
                }
                kf0n = __builtin_bit_cast(bf16x8, *(const u16x8*)(ksrc + (size_t)(nn + l31) * 8));
                kf1n = __builtin_bit_cast(bf16x8, *(const u16x8*)(ksrc + (size_t)(nn + 32 + l31) * 8));
            }

            // ---- QK: E C-layout col=q (l31), row=key (r&3)+8(r>>2)+4h (E1: +32)
            f32x16 E0 = __builtin_amdgcn_mfma_f32_32x32x16_bf16(kf0c, qf, zro, 0, 0, 0);
            f32x16 E1 = __builtin_amdgcn_mfma_f32_32x32x16_bf16(kf1c, qf, zro, 0, 0, 0);

            // ---- p = 2^(E-32); pack row-pairs -> u32 bf16x2
            unsigned int pk0[8], q0s[8], pk1[8], q1s[8];
#pragma unroll
            for (int g = 0; g < 8; ++g) {
                float pa = fexp2(E0[2 * g] - MSTAT);
                float pb = fexp2(E0[2 * g + 1] - MSTAT);
                sA += pa; sB += pb;
                pk0[g] = packbf(pa, pb);
            }
#pragma unroll
            for (int g = 0; g < 8; ++g)
                q0s[g] = (unsigned int)__shfl_xor((int)pk0[g], 32, 64);
#pragma unroll
            for (int g = 0; g < 8; ++g) {
                float pa = fexp2(E1[2 * g] - MSTAT);
                float pb = fexp2(E1[2 * g + 1] - MSTAT);
                sC += pa; sD += pb;
                pk1[g] = packbf(pa, pb);
            }
#pragma unroll
            for (int g = 0; g < 8; ++g)
                q1s[g] = (unsigned int)__shfl_xor((int)pk1[g], 32, 64);

            // ---- build PV B-frags: lane(l31=q,h) needs keys 16s2+8h+0..7
            uint4 pf[4];
#pragma unroll
            for (int s2 = 0; s2 < 2; ++s2) {
                const int ba = 4 * s2;
                pf[s2].x = h ? q0s[ba + 2] : pk0[ba];
                pf[s2].y = h ? q0s[ba + 3] : pk0[ba + 1];
                pf[s2].z = h ? pk0[ba + 2] : q0s[ba];
                pf[s2].w = h ? pk0[ba + 3] : q0s[ba + 1];
            }
#pragma unroll
            for (int s2 = 2; s2 < 4; ++s2) {
                const int ba = 4 * (s2 - 2);
                pf[s2].x = h ? q1s[ba + 2] : pk1[ba];
                pf[s2].y = h ? q1s[ba + 3] : pk1[ba + 1];
                pf[s2].z = h ? pk1[ba + 2] : q1s[ba];
                pf[s2].w = h ? pk1[ba + 3] : q1s[ba + 1];
            }

            // ---- PV with current-tile V (prefetched last iteration)
#pragma unroll
            for (int s2 = 0; s2 < 4; ++s2)
                acc0 = __builtin_amdgcn_mfma_f32_32x32x16_bf16(
                    __builtin_bit_cast(bf16x8, va0c[s2]),
                    __builtin_bit_cast(bf16x8, pf[s2]), acc0, 0, 0, 0);
#pragma unroll
            for (int s2 = 0; s2 < 4; ++s2)
                acc1 = __builtin_amdgcn_mfma_f32_32x32x16_bf16(
                    __builtin_bit_cast(bf16x8, va1c[s2]),
                    __builtin_bit_cast(bf16x8, pf[s2]), acc1, 0, 0, 0);

            if (pre) {
#pragma unroll
                for (int s2 = 0; s2 < 4; ++s2) { va0c[s2] = va0n[s2]; va1c[s2] = va1n[s2]; }
                kf0c = kf0n; kf1c = kf1n;
            }
        }
    }

    // ---- tree merge (plain sums, static m) ----
    l_sh[w * 64 + lane] = (sA + sB) + (sC + sD);
    float* mw = smem_f;
    auto wr = [&](int srcw) {
#pragma unroll
        for (int r4 = 0; r4 < 4; ++r4) {
            *(float4*)&mw[((size_t)(srcw * 2 + 0) * 64 + lane) * 16 + 4 * r4] =
                make_float4(acc0[4*r4], acc0[4*r4+1], acc0[4*r4+2], acc0[4*r4+3]);
            *(float4*)&mw[((size_t)(srcw * 2 + 1) * 64 + lane) * 16 + 4 * r4] =
                make_float4(acc1[4*r4], acc1[4*r4+1], acc1[4*r4+2], acc1[4*r4+3]);
        }
    };
    auto rd = [&](int srcw) {
#pragma unroll
        for (int r4 = 0; r4 < 4; ++r4) {
            float4 a = *(const float4*)&mw[((size_t)(srcw * 2 + 0) * 64 + lane) * 16 + 4 * r4];
            float4 c = *(const float4*)&mw[((size_t)(srcw * 2 + 1) * 64 + lane) * 16 + 4 * r4];
            acc0[4*r4]   += a.x; acc0[4*r4+1] += a.y; acc0[4*r4+2] += a.z; acc0[4*r4+3] += a.w;
            acc1[4*r4]   += c.x; acc1[4*r4+1] += c.y; acc1[4*r4+2] += c.z; acc1[4*r4+3] += c.w;
        }
    };
    if (w >= 4) wr(w - 4);
    __syncthreads();
    if (w < 4) rd(w);
    __syncthreads();
    if (w >= 2 && w < 4) wr(w - 2);
    __syncthreads();
    if (w < 2) rd(w);
    __syncthreads();
    if (w == 1) wr(0);
    __syncthreads();
    if (w == 0) {
        rd(0);
        float l_tot = 0.0f;
#pragma unroll
        for (int ww = 0; ww < 8; ++ww)
            l_tot += l_sh[ww * 64 + l31] + l_sh[ww * 64 + 32 + l31];
        const float inv = 1.0f / l_tot;
        const float g = gamma[0];
#pragma unroll
        for (int r = 0; r < 16; ++r) {
            int c = (r & 3) + 8 * (r >> 2) + 4 * h;
            size_t i0 = ((size_t)b * 64 + c) * NVOX + m0 + l31;
            size_t i1 = ((size_t)b * 64 + c + 32) * NVOX + m0 + l31;
            out[i0] = g * (acc0[r] * inv) + x[i0];
            out[i1] = g * (acc1[r] * inv) + x[i1];
        }
    }
}

// ---------------------------------------------------------------------------
extern "C" void kernel_launch(void* const* d_in, const int* in_sizes, int n_in,
                              void* d_out, int out_size, void* d_ws, size_t ws_size,
                              hipStream_t stream) {
    const float* x     = (const float*)d_in[0];
    const float* wq    = (const float*)d_in[1];
    const float* bq    = (const float*)d_in[2];
    const float* wk    = (const float*)d_in[3];
    const float* bk    = (const float*)d_in[4];
    const float* wv    = (const float*)d_in[5];
    const float* bv    = (const float*)d_in[6];
    const float* gamma = (const float*)d_in[7];
    float* out = (float*)d_out;

    unsigned short* qws = (unsigned short*)d_ws;            // [16000][16] hi|lo (log2e-scaled)
    unsigned short* kws = qws + (size_t)BATCH * NVOX * 16;  // [16000][8]
    unsigned short* vws = kws + (size_t)BATCH * NVOX * 8;   // [2][64][8000]

    qkv_kernel<<<1000, 192, 0, stream>>>(x, wq, bq, wk, bk, wv, bv, qws, kws, vws);
    attn_kernel<<<BATCH * QTILES, 512, 0, stream>>>(qws, kws, vws, x, gamma, out);
}

// Round 7
// 145.778 us; speedup vs baseline: 2.3032x; 2.3032x over previous
//
#include <hip/hip_runtime.h>
#include <math.h>

#define BATCH  2
#define NVOX   8000
#define MT     32            // queries per attn block
#define KT     64            // keys per tile
#define NTILES 125
#define QTILES 250
#define LOG2E  1.44269504f
#define MSTAT  32.0f         // static softmax shift (log2 domain)

typedef float  f32x16 __attribute__((ext_vector_type(16)));
typedef __bf16 bf16x8 __attribute__((ext_vector_type(8)));
typedef unsigned short u16x8 __attribute__((ext_vector_type(8)));

__device__ __forceinline__ unsigned short f2bf(float f) {
    return __builtin_bit_cast(unsigned short, (__bf16)f);
}
__device__ __forceinline__ unsigned int packbf(float lo, float hi) {
    return (unsigned int)f2bf(lo) | ((unsigned int)f2bf(hi) << 16);
}
// 2^x via v_exp_f32; s_nop covers the trans->VALU wait state.
__device__ __forceinline__ float fexp2(float x) {
    float r;
    asm("v_exp_f32 %0, %1\n\ts_nop 0" : "=v"(r) : "v"(x));
    return r;
}

// ---------------------------------------------------------------------------
// Kernel 1: projection GEMM. 1000 blocks x 192 thr, 16 voxels per block.
// W fragments converted in-kernel from fp32 (L2-broadcast), LOG2E folded into
// q rows. Epilogue transposes through LDS -> all global stores 16B coalesced.
// ---------------------------------------------------------------------------
__global__ __launch_bounds__(192) void qkv_kernel(
    const float* __restrict__ x,
    const float* __restrict__ wq, const float* __restrict__ bq,
    const float* __restrict__ wk, const float* __restrict__ bk,
    const float* __restrict__ wv, const float* __restrict__ bv,
    unsigned short* __restrict__ qws, unsigned short* __restrict__ kws,
    unsigned short* __restrict__ vws)
{
    __shared__ __align__(16) unsigned short st[88 * 24];  // rows: 0-7 q-hi, 8-15 k, 16-79 v, 80-87 q-lo
    const int t = threadIdx.x, lane = t & 63, ot = t >> 6;
    const int l31 = lane & 31, h = lane >> 5;
    const int blk = blockIdx.x, b = blk / 500, v0 = (blk % 500) * 16;
    const int nL = v0 + (l31 & 15);               // duplicate cols 16-31 (junk, unstored)

    const int o = ot * 32 + l31;
    const float* wsrc;
    float scale = 1.0f;
    if (o < 8)       { wsrc = wq + o * 64; scale = LOG2E; }
    else if (o < 16) { wsrc = wk + (o - 8) * 64; }
    else             { wsrc = wv + ((o - 16) & 63) * 64; }

    bf16x8 Ah[4], Al[4];
#pragma unroll
    for (int cc = 0; cc < 4; ++cc) {
        float4 w0 = *(const float4*)(wsrc + cc * 16 + 8 * h);
        float4 w1 = *(const float4*)(wsrc + cc * 16 + 8 * h + 4);
        float wf[8] = { w0.x, w0.y, w0.z, w0.w, w1.x, w1.y, w1.z, w1.w };
        unsigned short hh[8], ll[8];
#pragma unroll
        for (int j = 0; j < 8; ++j) {
            float wv_ = wf[j] * scale;
            __bf16 hb = (__bf16)wv_;
            hh[j] = __builtin_bit_cast(unsigned short, hb);
            ll[j] = f2bf(wv_ - (float)hb);
        }
        Ah[cc] = __builtin_bit_cast(bf16x8, *(u16x8*)hh);
        Al[cc] = __builtin_bit_cast(bf16x8, *(u16x8*)ll);
    }

    bf16x8 Bhi[4], Blo[4];
    const float* xb = x + (size_t)b * 64 * NVOX + nL;
#pragma unroll
    for (int cc = 0; cc < 4; ++cc) {
        unsigned short bh[8], bl[8];
#pragma unroll
        for (int j = 0; j < 8; ++j) {
            float xf = xb[(size_t)(cc * 16 + 8 * h + j) * NVOX];
            __bf16 xh = (__bf16)xf;
            bh[j] = __builtin_bit_cast(unsigned short, xh);
            bl[j] = f2bf(xf - (float)xh);
        }
        Bhi[cc] = __builtin_bit_cast(bf16x8, *(u16x8*)bh);
        Blo[cc] = __builtin_bit_cast(bf16x8, *(u16x8*)bl);
    }

    f32x16 acc;
#pragma unroll
    for (int r = 0; r < 16; ++r) acc[r] = 0.0f;
#pragma unroll
    for (int cc = 0; cc < 4; ++cc) {
        acc = __builtin_amdgcn_mfma_f32_32x32x16_bf16(Ah[cc], Bhi[cc], acc, 0, 0, 0);
        acc = __builtin_amdgcn_mfma_f32_32x32x16_bf16(Al[cc], Bhi[cc], acc, 0, 0, 0);
        acc = __builtin_amdgcn_mfma_f32_32x32x16_bf16(Ah[cc], Blo[cc], acc, 0, 0, 0);
    }

    if (l31 < 16) {
#pragma unroll
        for (int r = 0; r < 16; ++r) {
            int oo = ot * 32 + (r & 3) + 8 * (r >> 2) + 4 * h;
            if (oo >= 80) continue;
            float bias = (oo < 8) ? bq[oo] * LOG2E : (oo < 16) ? bk[oo - 8] : bv[oo - 16];
            float v = acc[r] + bias;
            if (oo < 8) {
                __bf16 hb = (__bf16)v;
                st[oo * 24 + l31]        = __builtin_bit_cast(unsigned short, hb);
                st[(80 + oo) * 24 + l31] = f2bf(v - (float)hb);
            } else {
                st[oo * 24 + l31] = f2bf(v);
            }
        }
    }
    __syncthreads();

    if (t < 128) {                       // vws: 64 ch x 2 chunks of 8 vox
        int ch = t >> 1, part = t & 1;
        uint4 d = *(const uint4*)&st[(16 + ch) * 24 + part * 8];
        *(uint4*)(vws + ((size_t)b * 64 + ch) * NVOX + v0 + part * 8) = d;
    } else if (t < 160) {                // qws: 16 vox x {hi,lo}
        int i = t - 128, vox = i >> 1, half = i & 1;
        int rbase = half ? 80 : 0;
        unsigned short g[8];
#pragma unroll
        for (int r = 0; r < 8; ++r) g[r] = st[(rbase + r) * 24 + vox];
        *(uint4*)(qws + (size_t)(b * NVOX + v0 + vox) * 16 + half * 8) = *(uint4*)g;
    } else if (t < 176) {                // kws: 16 vox
        int vox = t - 160;
        unsigned short g[8];
#pragma unroll
        for (int r = 0; r < 8; ++r) g[r] = st[(8 + r) * 24 + vox];
        *(uint4*)(kws + (size_t)(b * NVOX + v0 + vox) * 8) = *(uint4*)g;
    }
}

// ---------------------------------------------------------------------------
// Kernel 2: flash attention, static-m softmax, zero main-loop barriers/LDS.
//   500 blocks x 512 thr (8 waves). Wave w owns tiles T = w+8S.
//   Software-pipelined by one tile: PV for tile T-1 issues while tile T's
//   shfl transpose is in flight (DS latency hidden under MFMA issue).
//   launch_bounds(512,1): keep the VGPR cap high — R6 showed a tight cap
//   makes the allocator spill prefetch state to scratch (WRITE_SIZE 708MB).
// ---------------------------------------------------------------------------
__global__ __launch_bounds__(512, 1) void attn_kernel(
    const unsigned short* __restrict__ qws, const unsigned short* __restrict__ kws,
    const unsigned short* __restrict__ vws, const float* __restrict__ x,
    const float* __restrict__ gamma, float* __restrict__ out)
{
    __shared__ float smem_f[8704];          // 32KB merge + 2KB l
    float* l_sh = smem_f + 8192;            // [8][64]

    const int blk = blockIdx.x, b = blk / QTILES, m0 = (blk % QTILES) * MT;
    const int t = threadIdx.x, lane = t & 63, w = t >> 6;
    const int l31 = lane & 31, h = lane >> 5;

    // Q B-frag (log2e pre-folded): col=query l31, h=0 hi / h=1 lo
    const bf16x8 qf = __builtin_bit_cast(bf16x8,
        *(const u16x8*)(qws + (size_t)(b * NVOX + m0 + l31) * 16 + h * 8));

    const unsigned short* ksrc = kws + (size_t)b * NVOX * 8;
    const unsigned short* vb0  = vws + ((size_t)b * 64 + l31) * NVOX + 8 * h;
    const unsigned short* vb1  = vb0 + (size_t)32 * NVOX;

    f32x16 acc0, acc1, zro;
#pragma unroll
    for (int r = 0; r < 16; ++r) { acc0[r] = 0.0f; acc1[r] = 0.0f; zro[r] = 0.0f; }
    float sA = 0.0f, sB = 0.0f, sC = 0.0f, sD = 0.0f;

    // pipeline state
    uint4 va0[4], va1[4];                   // V frags for tile T (PV'd next iter)
    uint4 pf[4];                            // P B-frags for tile T
    bf16x8 kf0c = __builtin_bit_cast(bf16x8, *(const u16x8*)(ksrc + (size_t)(w * KT + l31) * 8));
    bf16x8 kf1c = __builtin_bit_cast(bf16x8, *(const u16x8*)(ksrc + (size_t)(w * KT + 32 + l31) * 8));
    bool havePrev = false;

#pragma unroll 1
    for (int S = 0; S < 16; ++S) {
        const int T = w + 8 * S;
        if (T < NTILES) {
            const int n0 = T * KT;
            const int Tn = T + 8;

            // ---- prefetch K for tile T+8 (kf_c dies right after the QK MFMAs)
            bf16x8 kf0n = kf0c, kf1n = kf1c;
            if (Tn < NTILES) {
                const int nn = Tn * KT;
                kf0n = __builtin_bit_cast(bf16x8, *(const u16x8*)(ksrc + (size_t)(nn + l31) * 8));
                kf1n = __builtin_bit_cast(bf16x8, *(const u16x8*)(ksrc + (size_t)(nn + 32 + l31) * 8));
            }

            // ---- QK: E C-layout col=q (l31), row=key (r&3)+8(r>>2)+4h (E1: +32)
            f32x16 E0 = __builtin_amdgcn_mfma_f32_32x32x16_bf16(kf0c, qf, zro, 0, 0, 0);
            f32x16 E1 = __builtin_amdgcn_mfma_f32_32x32x16_bf16(kf1c, qf, zro, 0, 0, 0);
            kf0c = kf0n; kf1c = kf1n;

            // ---- p = 2^(E-32); pack row-pairs -> u32 bf16x2
            unsigned int pk0[8], q0s[8], pk1[8], q1s[8];
#pragma unroll
            for (int g = 0; g < 8; ++g) {
                float pa = fexp2(E0[2 * g] - MSTAT);
                float pb = fexp2(E0[2 * g + 1] - MSTAT);
                sA += pa; sB += pb;
                pk0[g] = packbf(pa, pb);
            }
#pragma unroll
            for (int g = 0; g < 8; ++g) {
                float pa = fexp2(E1[2 * g] - MSTAT);
                float pb = fexp2(E1[2 * g + 1] - MSTAT);
                sC += pa; sD += pb;
                pk1[g] = packbf(pa, pb);
            }
            // ---- issue the cross-half exchange (DS); consumed after PV below
#pragma unroll
            for (int g = 0; g < 8; ++g)
                q0s[g] = (unsigned int)__shfl_xor((int)pk0[g], 32, 64);
#pragma unroll
            for (int g = 0; g < 8; ++g)
                q1s[g] = (unsigned int)__shfl_xor((int)pk1[g], 32, 64);

            // ---- PV for tile T-1 (pf/va from last iter) — hides DS latency
            if (havePrev) {
#pragma unroll
                for (int s2 = 0; s2 < 4; ++s2)
                    acc0 = __builtin_amdgcn_mfma_f32_32x32x16_bf16(
                        __builtin_bit_cast(bf16x8, va0[s2]),
                        __builtin_bit_cast(bf16x8, pf[s2]), acc0, 0, 0, 0);
#pragma unroll
                for (int s2 = 0; s2 < 4; ++s2)
                    acc1 = __builtin_amdgcn_mfma_f32_32x32x16_bf16(
                        __builtin_bit_cast(bf16x8, va1[s2]),
                        __builtin_bit_cast(bf16x8, pf[s2]), acc1, 0, 0, 0);
            }

            // ---- V loads for THIS tile (consumed next iter; full iter to land)
#pragma unroll
            for (int s2 = 0; s2 < 4; ++s2) {
                va0[s2] = *(const uint4*)(vb0 + n0 + 16 * s2);
                va1[s2] = *(const uint4*)(vb1 + n0 + 16 * s2);
            }

            // ---- build PV B-frags for tile T: lane(l31=q,h) needs keys 16s2+8h+0..7
#pragma unroll
            for (int s2 = 0; s2 < 2; ++s2) {
                const int ba = 4 * s2;
                pf[s2].x = h ? q0s[ba + 2] : pk0[ba];
                pf[s2].y = h ? q0s[ba + 3] : pk0[ba + 1];
                pf[s2].z = h ? pk0[ba + 2] : q0s[ba];
                pf[s2].w = h ? pk0[ba + 3] : q0s[ba + 1];
            }
#pragma unroll
            for (int s2 = 2; s2 < 4; ++s2) {
                const int ba = 4 * (s2 - 2);
                pf[s2].x = h ? q1s[ba + 2] : pk1[ba];
                pf[s2].y = h ? q1s[ba + 3] : pk1[ba + 1];
                pf[s2].z = h ? pk1[ba + 2] : q1s[ba];
                pf[s2].w = h ? pk1[ba + 3] : q1s[ba + 1];
            }
            havePrev = true;
        }
    }

    // ---- drain: PV for the last tile
#pragma unroll
    for (int s2 = 0; s2 < 4; ++s2)
        acc0 = __builtin_amdgcn_mfma_f32_32x32x16_bf16(
            __builtin_bit_cast(bf16x8, va0[s2]),
            __builtin_bit_cast(bf16x8, pf[s2]), acc0, 0, 0, 0);
#pragma unroll
    for (int s2 = 0; s2 < 4; ++s2)
        acc1 = __builtin_amdgcn_mfma_f32_32x32x16_bf16(
            __builtin_bit_cast(bf16x8, va1[s2]),
            __builtin_bit_cast(bf16x8, pf[s2]), acc1, 0, 0, 0);

    // ---- tree merge (plain sums, static m) ----
    l_sh[w * 64 + lane] = (sA + sB) + (sC + sD);
    float* mw = smem_f;
    auto wr = [&](int srcw) {
#pragma unroll
        for (int r4 = 0; r4 < 4; ++r4) {
            *(float4*)&mw[((size_t)(srcw * 2 + 0) * 64 + lane) * 16 + 4 * r4] =
                make_float4(acc0[4*r4], acc0[4*r4+1], acc0[4*r4+2], acc0[4*r4+3]);
            *(float4*)&mw[((size_t)(srcw * 2 + 1) * 64 + lane) * 16 + 4 * r4] =
                make_float4(acc1[4*r4], acc1[4*r4+1], acc1[4*r4+2], acc1[4*r4+3]);
        }
    };
    auto rd = [&](int srcw) {
#pragma unroll
        for (int r4 = 0; r4 < 4; ++r4) {
            float4 a = *(const float4*)&mw[((size_t)(srcw * 2 + 0) * 64 + lane) * 16 + 4 * r4];
            float4 c = *(const float4*)&mw[((size_t)(srcw * 2 + 1) * 64 + lane) * 16 + 4 * r4];
            acc0[4*r4]   += a.x; acc0[4*r4+1] += a.y; acc0[4*r4+2] += a.z; acc0[4*r4+3] += a.w;
            acc1[4*r4]   += c.x; acc1[4*r4+1] += c.y; acc1[4*r4+2] += c.z; acc1[4*r4+3] += c.w;
        }
    };
    if (w >= 4) wr(w - 4);
    __syncthreads();
    if (w < 4) rd(w);
    __syncthreads();
    if (w >= 2 && w < 4) wr(w - 2);
    __syncthreads();
    if (w < 2) rd(w);
    __syncthreads();
    if (w == 1) wr(0);
    __syncthreads();
    if (w == 0) {
        rd(0);
        float l_tot = 0.0f;
#pragma unroll
        for (int ww = 0; ww < 8; ++ww)
            l_tot += l_sh[ww * 64 + l31] + l_sh[ww * 64 + 32 + l31];
        const float inv = 1.0f / l_tot;
        const float g = gamma[0];
#pragma unroll
        for (int r = 0; r < 16; ++r) {
            int c = (r & 3) + 8 * (r >> 2) + 4 * h;
            size_t i0 = ((size_t)b * 64 + c) * NVOX + m0 + l31;
            size_t i1 = ((size_t)b * 64 + c + 32) * NVOX + m0 + l31;
            out[i0] = g * (acc0[r] * inv) + x[i0];
            out[i1] = g * (acc1[r] * inv) + x[i1];
        }
    }
}

// ---------------------------------------------------------------------------
extern "C" void kernel_launch(void* const* d_in, const int* in_sizes, int n_in,
                              void* d_out, int out_size, void* d_ws, size_t ws_size,
                              hipStream_t stream) {
    const float* x     = (const float*)d_in[0];
    const float* wq    = (const float*)d_in[1];
    const float* bq    = (const float*)d_in[2];
    const float* wk    = (const float*)d_in[3];
    const float* bk    = (const float*)d_in[4];
    const float* wv    = (const float*)d_in[5];
    const float* bv    = (const float*)d_in[6];
    const float* gamma = (const float*)d_in[7];
    float* out = (float*)d_out;

    unsigned short* qws = (unsigned short*)d_ws;            // [16000][16] hi|lo (log2e-scaled)
    unsigned short* kws = qws + (size_t)BATCH * NVOX * 16;  // [16000][8]
    unsigned short* vws = kws + (size_t)BATCH * NVOX * 8;   // [2][64][8000]

    qkv_kernel<<<1000, 192, 0, stream>>>(x, wq, bq, wk, bk, wv, bv, qws, kws, vws);
    attn_kernel<<<BATCH * QTILES, 512, 0, stream>>>(qws, kws, vws, x, gamma, out);
}

// Round 8
// 121.496 us; speedup vs baseline: 2.7635x; 1.1999x over previous
//
#include <hip/hip_runtime.h>
#include <math.h>

#define BATCH  2
#define NVOX   8000
#define MT     32            // queries per attn block
#define KT     64            // keys per tile
#define NTILES 125
#define QTILES 250
#define LOG2E  1.44269504f
#define MSTAT  32.0f         // static softmax shift (log2 domain)

typedef float  f32x16 __attribute__((ext_vector_type(16)));
typedef __bf16 bf16x8 __attribute__((ext_vector_type(8)));
typedef unsigned short u16x8 __attribute__((ext_vector_type(8)));

__device__ __forceinline__ unsigned short f2bf(float f) {
    return __builtin_bit_cast(unsigned short, (__bf16)f);
}
__device__ __forceinline__ unsigned int packbf(float lo, float hi) {
    return (unsigned int)f2bf(lo) | ((unsigned int)f2bf(hi) << 16);
}
// 2^x via v_exp_f32; s_nop covers the trans->VALU wait state.
__device__ __forceinline__ float fexp2(float x) {
    float r;
    asm("v_exp_f32 %0, %1\n\ts_nop 0" : "=v"(r) : "v"(x));
    return r;
}

// V workspace layout: FRAGMENT-LINEAR, so attn's A-frag loads are contiguous.
//   u16 index = (((b*125+T)*4 + s2)*2 + cg)*2 + h)*256 + c31*8 + j
//   = (b*125+T)*4096 + s2*1024 + cg*512 + h*256 + c31*8 + j
// One PV A-frag wave-load (fixed T,s2,cg; lanes (l31,h)) covers two contiguous
// 512B runs -> 8 cache lines vs 64 with the planar [c][n] layout (R7's
// hidden bottleneck: 64-line gathers saturated L1-tag/L2-request bandwidth).

// ---------------------------------------------------------------------------
// Kernel 1: projection GEMM. 1000 blocks x 192 thr, 16 voxels per block.
// W fragments converted in-kernel from fp32 (L2-broadcast), LOG2E folded into
// q rows. Epilogue transposes through LDS -> all global stores 16B coalesced.
// ---------------------------------------------------------------------------
__global__ __launch_bounds__(192) void qkv_kernel(
    const float* __restrict__ x,
    const float* __restrict__ wq, const float* __restrict__ bq,
    const float* __restrict__ wk, const float* __restrict__ bk,
    const float* __restrict__ wv, const float* __restrict__ bv,
    unsigned short* __restrict__ qws, unsigned short* __restrict__ kws,
    unsigned short* __restrict__ vws)
{
    __shared__ __align__(16) unsigned short st[88 * 24];  // rows: 0-7 q-hi, 8-15 k, 16-79 v, 80-87 q-lo
    const int t = threadIdx.x, lane = t & 63, ot = t >> 6;
    const int l31 = lane & 31, h = lane >> 5;
    const int blk = blockIdx.x, b = blk / 500, v0 = (blk % 500) * 16;
    const int nL = v0 + (l31 & 15);               // duplicate cols 16-31 (junk, unstored)

    const int o = ot * 32 + l31;
    const float* wsrc;
    float scale = 1.0f;
    if (o < 8)       { wsrc = wq + o * 64; scale = LOG2E; }
    else if (o < 16) { wsrc = wk + (o - 8) * 64; }
    else             { wsrc = wv + ((o - 16) & 63) * 64; }

    bf16x8 Ah[4], Al[4];
#pragma unroll
    for (int cc = 0; cc < 4; ++cc) {
        float4 w0 = *(const float4*)(wsrc + cc * 16 + 8 * h);
        float4 w1 = *(const float4*)(wsrc + cc * 16 + 8 * h + 4);
        float wf[8] = { w0.x, w0.y, w0.z, w0.w, w1.x, w1.y, w1.z, w1.w };
        unsigned short hh[8], ll[8];
#pragma unroll
        for (int j = 0; j < 8; ++j) {
            float wv_ = wf[j] * scale;
            __bf16 hb = (__bf16)wv_;
            hh[j] = __builtin_bit_cast(unsigned short, hb);
            ll[j] = f2bf(wv_ - (float)hb);
        }
        Ah[cc] = __builtin_bit_cast(bf16x8, *(u16x8*)hh);
        Al[cc] = __builtin_bit_cast(bf16x8, *(u16x8*)ll);
    }

    bf16x8 Bhi[4], Blo[4];
    const float* xb = x + (size_t)b * 64 * NVOX + nL;
#pragma unroll
    for (int cc = 0; cc < 4; ++cc) {
        unsigned short bh[8], bl[8];
#pragma unroll
        for (int j = 0; j < 8; ++j) {
            float xf = xb[(size_t)(cc * 16 + 8 * h + j) * NVOX];
            __bf16 xh = (__bf16)xf;
            bh[j] = __builtin_bit_cast(unsigned short, xh);
            bl[j] = f2bf(xf - (float)xh);
        }
        Bhi[cc] = __builtin_bit_cast(bf16x8, *(u16x8*)bh);
        Blo[cc] = __builtin_bit_cast(bf16x8, *(u16x8*)bl);
    }

    f32x16 acc;
#pragma unroll
    for (int r = 0; r < 16; ++r) acc[r] = 0.0f;
#pragma unroll
    for (int cc = 0; cc < 4; ++cc) {
        acc = __builtin_amdgcn_mfma_f32_32x32x16_bf16(Ah[cc], Bhi[cc], acc, 0, 0, 0);
        acc = __builtin_amdgcn_mfma_f32_32x32x16_bf16(Al[cc], Bhi[cc], acc, 0, 0, 0);
        acc = __builtin_amdgcn_mfma_f32_32x32x16_bf16(Ah[cc], Blo[cc], acc, 0, 0, 0);
    }

    if (l31 < 16) {
#pragma unroll
        for (int r = 0; r < 16; ++r) {
            int oo = ot * 32 + (r & 3) + 8 * (r >> 2) + 4 * h;
            if (oo >= 80) continue;
            float bias = (oo < 8) ? bq[oo] * LOG2E : (oo < 16) ? bk[oo - 8] : bv[oo - 16];
            float v = acc[r] + bias;
            if (oo < 8) {
                __bf16 hb = (__bf16)v;
                st[oo * 24 + l31]        = __builtin_bit_cast(unsigned short, hb);
                st[(80 + oo) * 24 + l31] = f2bf(v - (float)hb);
            } else {
                st[oo * 24 + l31] = f2bf(v);
            }
        }
    }
    __syncthreads();

    if (t < 128) {                       // vws: 64 ch x 2 key-chunks of 8 -> fragment-linear slots
        int ch = t >> 1, p = t & 1;      // p = which 8-key half of this 16-voxel chunk
        int T = v0 >> 6, s2 = (v0 & 63) >> 4, cg = ch >> 5, c31 = ch & 31;
        uint4 d = *(const uint4*)&st[(16 + ch) * 24 + p * 8];
        size_t idx = ((size_t)((b * 125 + T) * 4 + s2) * 2 + cg) * 512
                   + (size_t)p * 256 + c31 * 8;
        *(uint4*)(vws + idx) = d;
    } else if (t < 160) {                // qws: 16 vox x {hi,lo}
        int i = t - 128, vox = i >> 1, half = i & 1;
        int rbase = half ? 80 : 0;
        unsigned short g[8];
#pragma unroll
        for (int r = 0; r < 8; ++r) g[r] = st[(rbase + r) * 24 + vox];
        *(uint4*)(qws + (size_t)(b * NVOX + v0 + vox) * 16 + half * 8) = *(uint4*)g;
    } else if (t < 176) {                // kws: 16 vox
        int vox = t - 160;
        unsigned short g[8];
#pragma unroll
        for (int r = 0; r < 8; ++r) g[r] = st[(8 + r) * 24 + vox];
        *(uint4*)(kws + (size_t)(b * NVOX + v0 + vox) * 8) = *(uint4*)g;
    }
}

// ---------------------------------------------------------------------------
// Kernel 2: flash attention, static-m softmax, zero main-loop barriers/LDS.
//   500 blocks x 512 thr (8 waves). Wave w owns tiles T = w+8S.
//   V loads are contiguous fragment-linear reads (8 lines/wave-load).
//   Pipelined by one tile: PV(T-1) issues under tile T's shfl transpose.
// ---------------------------------------------------------------------------
__global__ __launch_bounds__(512, 1) void attn_kernel(
    const unsigned short* __restrict__ qws, const unsigned short* __restrict__ kws,
    const unsigned short* __restrict__ vws, const float* __restrict__ x,
    const float* __restrict__ gamma, float* __restrict__ out)
{
    __shared__ float smem_f[8704];          // 32KB merge + 2KB l
    float* l_sh = smem_f + 8192;            // [8][64]

    const int blk = blockIdx.x, b = blk / QTILES, m0 = (blk % QTILES) * MT;
    const int t = threadIdx.x, lane = t & 63, w = t >> 6;
    const int l31 = lane & 31, h = lane >> 5;

    // Q B-frag (log2e pre-folded): col=query l31, h=0 hi / h=1 lo
    const bf16x8 qf = __builtin_bit_cast(bf16x8,
        *(const u16x8*)(qws + (size_t)(b * NVOX + m0 + l31) * 16 + h * 8));

    const unsigned short* ksrc = kws + (size_t)b * NVOX * 8;
    // fragment-linear V base for this lane: + T*4096 + s2*1024 (+512 for cg=1)
    const unsigned short* vbase = vws + (size_t)b * 512000 + h * 256 + l31 * 8;

    f32x16 acc0, acc1, zro;
#pragma unroll
    for (int r = 0; r < 16; ++r) { acc0[r] = 0.0f; acc1[r] = 0.0f; zro[r] = 0.0f; }
    float sA = 0.0f, sB = 0.0f, sC = 0.0f, sD = 0.0f;

    // pipeline state
    uint4 va0[4], va1[4];                   // V frags for tile T (PV'd next iter)
    uint4 pf[4];                            // P B-frags for tile T
    bf16x8 kf0c = __builtin_bit_cast(bf16x8, *(const u16x8*)(ksrc + (size_t)(w * KT + l31) * 8));
    bf16x8 kf1c = __builtin_bit_cast(bf16x8, *(const u16x8*)(ksrc + (size_t)(w * KT + 32 + l31) * 8));
    bool havePrev = false;

#pragma unroll 1
    for (int S = 0; S < 16; ++S) {
        const int T = w + 8 * S;
        if (T < NTILES) {
            const int Tn = T + 8;

            // ---- prefetch K for tile T+8 (kf_c dies right after the QK MFMAs)
            bf16x8 kf0n = kf0c, kf1n = kf1c;
            if (Tn < NTILES) {
                const int nn = Tn * KT;
                kf0n = __builtin_bit_cast(bf16x8, *(const u16x8*)(ksrc + (size_t)(nn + l31) * 8));
                kf1n = __builtin_bit_cast(bf16x8, *(const u16x8*)(ksrc + (size_t)(nn + 32 + l31) * 8));
            }

            // ---- QK: E C-layout col=q (l31), row=key (r&3)+8(r>>2)+4h (E1: +32)
            f32x16 E0 = __builtin_amdgcn_mfma_f32_32x32x16_bf16(kf0c, qf, zro, 0, 0, 0);
            f32x16 E1 = __builtin_amdgcn_mfma_f32_32x32x16_bf16(kf1c, qf, zro, 0, 0, 0);
            kf0c = kf0n; kf1c = kf1n;

            // ---- p = 2^(E-32); pack row-pairs -> u32 bf16x2
            unsigned int pk0[8], q0s[8], pk1[8], q1s[8];
#pragma unroll
            for (int g = 0; g < 8; ++g) {
                float pa = fexp2(E0[2 * g] - MSTAT);
                float pb = fexp2(E0[2 * g + 1] - MSTAT);
                sA += pa; sB += pb;
                pk0[g] = packbf(pa, pb);
            }
#pragma unroll
            for (int g = 0; g < 8; ++g) {
                float pa = fexp2(E1[2 * g] - MSTAT);
                float pb = fexp2(E1[2 * g + 1] - MSTAT);
                sC += pa; sD += pb;
                pk1[g] = packbf(pa, pb);
            }
            // ---- issue the cross-half exchange (DS); consumed after PV below
#pragma unroll
            for (int g = 0; g < 8; ++g)
                q0s[g] = (unsigned int)__shfl_xor((int)pk0[g], 32, 64);
#pragma unroll
            for (int g = 0; g < 8; ++g)
                q1s[g] = (unsigned int)__shfl_xor((int)pk1[g], 32, 64);

            // ---- PV for tile T-1 (pf/va from last iter) — hides DS latency
            if (havePrev) {
#pragma unroll
                for (int s2 = 0; s2 < 4; ++s2)
                    acc0 = __builtin_amdgcn_mfma_f32_32x32x16_bf16(
                        __builtin_bit_cast(bf16x8, va0[s2]),
                        __builtin_bit_cast(bf16x8, pf[s2]), acc0, 0, 0, 0);
#pragma unroll
                for (int s2 = 0; s2 < 4; ++s2)
                    acc1 = __builtin_amdgcn_mfma_f32_32x32x16_bf16(
                        __builtin_bit_cast(bf16x8, va1[s2]),
                        __builtin_bit_cast(bf16x8, pf[s2]), acc1, 0, 0, 0);
            }

            // ---- V loads for THIS tile (contiguous fragment-linear; land next iter)
            {
                const unsigned short* vt = vbase + (size_t)T * 4096;
#pragma unroll
                for (int s2 = 0; s2 < 4; ++s2) {
                    va0[s2] = *(const uint4*)(vt + s2 * 1024);
                    va1[s2] = *(const uint4*)(vt + s2 * 1024 + 512);
                }
            }

            // ---- build PV B-frags for tile T: lane(l31=q,h) needs keys 16s2+8h+0..7
#pragma unroll
            for (int s2 = 0; s2 < 2; ++s2) {
                const int ba = 4 * s2;
                pf[s2].x = h ? q0s[ba + 2] : pk0[ba];
                pf[s2].y = h ? q0s[ba + 3] : pk0[ba + 1];
                pf[s2].z = h ? pk0[ba + 2] : q0s[ba];
                pf[s2].w = h ? pk0[ba + 3] : q0s[ba + 1];
            }
#pragma unroll
            for (int s2 = 2; s2 < 4; ++s2) {
                const int ba = 4 * (s2 - 2);
                pf[s2].x = h ? q1s[ba + 2] : pk1[ba];
                pf[s2].y = h ? q1s[ba + 3] : pk1[ba + 1];
                pf[s2].z = h ? pk1[ba + 2] : q1s[ba];
                pf[s2].w = h ? pk1[ba + 3] : q1s[ba + 1];
            }
            havePrev = true;
        }
    }

    // ---- drain: PV for the last tile
#pragma unroll
    for (int s2 = 0; s2 < 4; ++s2)
        acc0 = __builtin_amdgcn_mfma_f32_32x32x16_bf16(
            __builtin_bit_cast(bf16x8, va0[s2]),
            __builtin_bit_cast(bf16x8, pf[s2]), acc0, 0, 0, 0);
#pragma unroll
    for (int s2 = 0; s2 < 4; ++s2)
        acc1 = __builtin_amdgcn_mfma_f32_32x32x16_bf16(
            __builtin_bit_cast(bf16x8, va1[s2]),
            __builtin_bit_cast(bf16x8, pf[s2]), acc1, 0, 0, 0);

    // ---- tree merge (plain sums, static m) ----
    l_sh[w * 64 + lane] = (sA + sB) + (sC + sD);
    float* mw = smem_f;
    auto wr = [&](int srcw) {
#pragma unroll
        for (int r4 = 0; r4 < 4; ++r4) {
            *(float4*)&mw[((size_t)(srcw * 2 + 0) * 64 + lane) * 16 + 4 * r4] =
                make_float4(acc0[4*r4], acc0[4*r4+1], acc0[4*r4+2], acc0[4*r4+3]);
            *(float4*)&mw[((size_t)(srcw * 2 + 1) * 64 + lane) * 16 + 4 * r4] =
                make_float4(acc1[4*r4], acc1[4*r4+1], acc1[4*r4+2], acc1[4*r4+3]);
        }
    };
    auto rd = [&](int srcw) {
#pragma unroll
        for (int r4 = 0; r4 < 4; ++r4) {
            float4 a = *(const float4*)&mw[((size_t)(srcw * 2 + 0) * 64 + lane) * 16 + 4 * r4];
            float4 c = *(const float4*)&mw[((size_t)(srcw * 2 + 1) * 64 + lane) * 16 + 4 * r4];
            acc0[4*r4]   += a.x; acc0[4*r4+1] += a.y; acc0[4*r4+2] += a.z; acc0[4*r4+3] += a.w;
            acc1[4*r4]   += c.x; acc1[4*r4+1] += c.y; acc1[4*r4+2] += c.z; acc1[4*r4+3] += c.w;
        }
    };
    if (w >= 4) wr(w - 4);
    __syncthreads();
    if (w < 4) rd(w);
    __syncthreads();
    if (w >= 2 && w < 4) wr(w - 2);
    __syncthreads();
    if (w < 2) rd(w);
    __syncthreads();
    if (w == 1) wr(0);
    __syncthreads();
    if (w == 0) {
        rd(0);
        float l_tot = 0.0f;
#pragma unroll
        for (int ww = 0; ww < 8; ++ww)
            l_tot += l_sh[ww * 64 + l31] + l_sh[ww * 64 + 32 + l31];
        const float inv = 1.0f / l_tot;
        const float g = gamma[0];
#pragma unroll
        for (int r = 0; r < 16; ++r) {
            int c = (r & 3) + 8 * (r >> 2) + 4 * h;
            size_t i0 = ((size_t)b * 64 + c) * NVOX + m0 + l31;
            size_t i1 = ((size_t)b * 64 + c + 32) * NVOX + m0 + l31;
            out[i0] = g * (acc0[r] * inv) + x[i0];
            out[i1] = g * (acc1[r] * inv) + x[i1];
        }
    }
}

// ---------------------------------------------------------------------------
extern "C" void kernel_launch(void* const* d_in, const int* in_sizes, int n_in,
                              void* d_out, int out_size, void* d_ws, size_t ws_size,
                              hipStream_t stream) {
    const float* x     = (const float*)d_in[0];
    const float* wq    = (const float*)d_in[1];
    const float* bq    = (const float*)d_in[2];
    const float* wk    = (const float*)d_in[3];
    const float* bk    = (const float*)d_in[4];
    const float* wv    = (const float*)d_in[5];
    const float* bv    = (const float*)d_in[6];
    const float* gamma = (const float*)d_in[7];
    float* out = (float*)d_out;

    unsigned short* qws = (unsigned short*)d_ws;            // [16000][16] hi|lo (log2e-scaled)
    unsigned short* kws = qws + (size_t)BATCH * NVOX * 16;  // [16000][8]
    unsigned short* vws = kws + (size_t)BATCH * NVOX * 8;   // [2][125][4][2][2][32][8] frag-linear

    qkv_kernel<<<1000, 192, 0, stream>>>(x, wq, bq, wk, bk, wv, bv, qws, kws, vws);
    attn_kernel<<<BATCH * QTILES, 512, 0, stream>>>(qws, kws, vws, x, gamma, out);
}

// Round 9
// 119.580 us; speedup vs baseline: 2.8077x; 1.0160x over previous
//
#include <hip/hip_runtime.h>
#include <math.h>

#define BATCH  2
#define NVOX   8000
#define MT     32            // queries per attn block
#define KT     64            // keys per tile
#define NTILES 125
#define QTILES 250
#define LOG2E  1.44269504f
#define MSTAT  32.0f         // static softmax shift (log2 domain)

typedef float  f32x16 __attribute__((ext_vector_type(16)));
typedef __bf16 bf16x8 __attribute__((ext_vector_type(8)));
typedef unsigned short u16x8 __attribute__((ext_vector_type(8)));

__device__ __forceinline__ unsigned short f2bf(float f) {
    return __builtin_bit_cast(unsigned short, (__bf16)f);
}
__device__ __forceinline__ unsigned int packbf(float lo, float hi) {
    return (unsigned int)f2bf(lo) | ((unsigned int)f2bf(hi) << 16);
}
// 2^x via v_exp_f32; s_nop covers the trans->VALU wait state.
__device__ __forceinline__ float fexp2(float x) {
    float r;
    asm("v_exp_f32 %0, %1\n\ts_nop 0" : "=v"(r) : "v"(x));
    return r;
}

// V workspace layout: FRAGMENT-LINEAR (R8 win: 8 lines per wave-load, not 64).
//   u16 index = (b*125+T)*4096 + s2*1024 + cg*512 + h*256 + c31*8 + j
//   holds V[c = cg*32+c31][key = T*64 + s2*16 + h*8 + j]

// ---------------------------------------------------------------------------
// Kernel 1: projection GEMM. 500 blocks x 192 thr, 32 voxels per block.
// R9: all 32 lanes carry DISTINCT voxels (R8 duplicated lanes 16-31 -> 2x
// wasted blocks/loads/MFMAs). x-loads are full 128B coalesced segments.
// W fragments converted in-kernel (L1/L2-broadcast), LOG2E folded into q rows.
// Epilogue transposes via LDS -> all global stores 16B coalesced.
// ---------------------------------------------------------------------------
__global__ __launch_bounds__(192) void qkv_kernel(
    const float* __restrict__ x,
    const float* __restrict__ wq, const float* __restrict__ bq,
    const float* __restrict__ wk, const float* __restrict__ bk,
    const float* __restrict__ wv, const float* __restrict__ bv,
    unsigned short* __restrict__ qws, unsigned short* __restrict__ kws,
    unsigned short* __restrict__ vws)
{
    // st rows: 0-7 q-hi, 8-15 k, 16-79 v, 80-87 q-lo; cols = 32 voxels; stride 40
    __shared__ __align__(16) unsigned short st[88 * 40];
    const int t = threadIdx.x, lane = t & 63, ot = t >> 6;   // ot 0..2
    const int l31 = lane & 31, h = lane >> 5;
    const int blk = blockIdx.x, b = blk / 250, v0 = (blk % 250) * 32;
    const int n = v0 + l31;                                  // 32 distinct voxels

    // ---- W A-frags: lane owns o-row ot*32+l31, cols cc*16+8h+0..7 ----
    const int o = ot * 32 + l31;
    const float* wsrc;
    float scale = 1.0f;
    if (o < 8)       { wsrc = wq + o * 64; scale = LOG2E; }
    else if (o < 16) { wsrc = wk + (o - 8) * 64; }
    else             { wsrc = wv + ((o - 16) & 63) * 64; }   // o>=80: junk, never stored

    bf16x8 Ah[4], Al[4];
#pragma unroll
    for (int cc = 0; cc < 4; ++cc) {
        float4 w0 = *(const float4*)(wsrc + cc * 16 + 8 * h);
        float4 w1 = *(const float4*)(wsrc + cc * 16 + 8 * h + 4);
        float wf[8] = { w0.x, w0.y, w0.z, w0.w, w1.x, w1.y, w1.z, w1.w };
        unsigned short hh[8], ll[8];
#pragma unroll
        for (int j = 0; j < 8; ++j) {
            float wv_ = wf[j] * scale;
            __bf16 hb = (__bf16)wv_;
            hh[j] = __builtin_bit_cast(unsigned short, hb);
            ll[j] = f2bf(wv_ - (float)hb);
        }
        Ah[cc] = __builtin_bit_cast(bf16x8, *(u16x8*)hh);
        Al[cc] = __builtin_bit_cast(bf16x8, *(u16x8*)ll);
    }

    // ---- X B-frags (hi/lo split); loads coalesced across 32 lanes (128B) ----
    bf16x8 Bhi[4], Blo[4];
    const float* xb = x + (size_t)b * 64 * NVOX + n;
#pragma unroll
    for (int cc = 0; cc < 4; ++cc) {
        unsigned short bh[8], bl[8];
#pragma unroll
        for (int j = 0; j < 8; ++j) {
            float xf = xb[(size_t)(cc * 16 + 8 * h + j) * NVOX];
            __bf16 xh = (__bf16)xf;
            bh[j] = __builtin_bit_cast(unsigned short, xh);
            bl[j] = f2bf(xf - (float)xh);
        }
        Bhi[cc] = __builtin_bit_cast(bf16x8, *(u16x8*)bh);
        Blo[cc] = __builtin_bit_cast(bf16x8, *(u16x8*)bl);
    }

    f32x16 acc;
#pragma unroll
    for (int r = 0; r < 16; ++r) acc[r] = 0.0f;
#pragma unroll
    for (int cc = 0; cc < 4; ++cc) {
        acc = __builtin_amdgcn_mfma_f32_32x32x16_bf16(Ah[cc], Bhi[cc], acc, 0, 0, 0);
        acc = __builtin_amdgcn_mfma_f32_32x32x16_bf16(Al[cc], Bhi[cc], acc, 0, 0, 0);
        acc = __builtin_amdgcn_mfma_f32_32x32x16_bf16(Ah[cc], Blo[cc], acc, 0, 0, 0);
    }

    // ---- stage C-layout results to LDS: lane holds (oo, vox = l31) ----
#pragma unroll
    for (int r = 0; r < 16; ++r) {
        int oo = ot * 32 + (r & 3) + 8 * (r >> 2) + 4 * h;
        if (oo >= 80) continue;
        float bias = (oo < 8) ? bq[oo] * LOG2E : (oo < 16) ? bk[oo - 8] : bv[oo - 16];
        float v = acc[r] + bias;
        if (oo < 8) {
            __bf16 hb = (__bf16)v;
            st[oo * 40 + l31]        = __builtin_bit_cast(unsigned short, hb);
            st[(80 + oo) * 40 + l31] = f2bf(v - (float)hb);
        } else {
            st[oo * 40 + l31] = f2bf(v);
        }
    }
    __syncthreads();

    // ---- coalesced 16B stores ----
    // vws: 256 units (64 ch x 4 key-chunks of 8) -> fragment-linear slots
    for (int idx = t; idx < 256; idx += 192) {
        int ch = idx >> 2, q = idx & 3;
        int T = v0 >> 6;
        int off = (v0 & 63) + q * 8;
        int s2 = off >> 4, p = (off >> 3) & 1;
        int cg = ch >> 5, c31 = ch & 31;
        size_t dst = ((size_t)(b * 125 + T)) * 4096 + s2 * 1024 + cg * 512
                   + p * 256 + c31 * 8;
        *(uint4*)(vws + dst) = *(const uint4*)&st[(16 + ch) * 40 + q * 8];
    }
    if (t >= 128) {                      // qws: 32 vox x {hi,lo} = 64 units
        int i = t - 128, vox = i >> 1, half = i & 1;
        int rbase = half ? 80 : 0;
        unsigned short g[8];
#pragma unroll
        for (int r = 0; r < 8; ++r) g[r] = st[(rbase + r) * 40 + vox];
        *(uint4*)(qws + (size_t)(b * NVOX + v0 + vox) * 16 + half * 8) = *(uint4*)g;
    } else if (t >= 96) {                // kws: 32 vox
        int vox = t - 96;
        unsigned short g[8];
#pragma unroll
        for (int r = 0; r < 8; ++r) g[r] = st[(8 + r) * 40 + vox];
        *(uint4*)(kws + (size_t)(b * NVOX + v0 + vox) * 8) = *(uint4*)g;
    }
}

// ---------------------------------------------------------------------------
// Kernel 2: flash attention — UNCHANGED from R8 (clean attribution baseline).
//   500 blocks x 512 thr (8 waves). Wave w owns tiles T = w+8S.
//   V loads contiguous fragment-linear; pipelined by one tile.
// ---------------------------------------------------------------------------
__global__ __launch_bounds__(512, 1) void attn_kernel(
    const unsigned short* __restrict__ qws, const unsigned short* __restrict__ kws,
    const unsigned short* __restrict__ vws, const float* __restrict__ x,
    const float* __restrict__ gamma, float* __restrict__ out)
{
    __shared__ float smem_f[8704];          // 32KB merge + 2KB l
    float* l_sh = smem_f + 8192;            // [8][64]

    const int blk = blockIdx.x, b = blk / QTILES, m0 = (blk % QTILES) * MT;
    const int t = threadIdx.x, lane = t & 63, w = t >> 6;
    const int l31 = lane & 31, h = lane >> 5;

    // Q B-frag (log2e pre-folded): col=query l31, h=0 hi / h=1 lo
    const bf16x8 qf = __builtin_bit_cast(bf16x8,
        *(const u16x8*)(qws + (size_t)(b * NVOX + m0 + l31) * 16 + h * 8));

    const unsigned short* ksrc = kws + (size_t)b * NVOX * 8;
    const unsigned short* vbase = vws + (size_t)b * 512000 + h * 256 + l31 * 8;

    f32x16 acc0, acc1, zro;
#pragma unroll
    for (int r = 0; r < 16; ++r) { acc0[r] = 0.0f; acc1[r] = 0.0f; zro[r] = 0.0f; }
    float sA = 0.0f, sB = 0.0f, sC = 0.0f, sD = 0.0f;

    uint4 va0[4], va1[4];
    uint4 pf[4];
    bf16x8 kf0c = __builtin_bit_cast(bf16x8, *(const u16x8*)(ksrc + (size_t)(w * KT + l31) * 8));
    bf16x8 kf1c = __builtin_bit_cast(bf16x8, *(const u16x8*)(ksrc + (size_t)(w * KT + 32 + l31) * 8));
    bool havePrev = false;

#pragma unroll 1
    for (int S = 0; S < 16; ++S) {
        const int T = w + 8 * S;
        if (T < NTILES) {
            const int Tn = T + 8;

            bf16x8 kf0n = kf0c, kf1n = kf1c;
            if (Tn < NTILES) {
                const int nn = Tn * KT;
                kf0n = __builtin_bit_cast(bf16x8, *(const u16x8*)(ksrc + (size_t)(nn + l31) * 8));
                kf1n = __builtin_bit_cast(bf16x8, *(const u16x8*)(ksrc + (size_t)(nn + 32 + l31) * 8));
            }

            f32x16 E0 = __builtin_amdgcn_mfma_f32_32x32x16_bf16(kf0c, qf, zro, 0, 0, 0);
            f32x16 E1 = __builtin_amdgcn_mfma_f32_32x32x16_bf16(kf1c, qf, zro, 0, 0, 0);
            kf0c = kf0n; kf1c = kf1n;

            unsigned int pk0[8], q0s[8], pk1[8], q1s[8];
#pragma unroll
            for (int g = 0; g < 8; ++g) {
                float pa = fexp2(E0[2 * g] - MSTAT);
                float pb = fexp2(E0[2 * g + 1] - MSTAT);
                sA += pa; sB += pb;
                pk0[g] = packbf(pa, pb);
            }
#pragma unroll
            for (int g = 0; g < 8; ++g) {
                float pa = fexp2(E1[2 * g] - MSTAT);
                float pb = fexp2(E1[2 * g + 1] - MSTAT);
                sC += pa; sD += pb;
                pk1[g] = packbf(pa, pb);
            }
#pragma unroll
            for (int g = 0; g < 8; ++g)
                q0s[g] = (unsigned int)__shfl_xor((int)pk0[g], 32, 64);
#pragma unroll
            for (int g = 0; g < 8; ++g)
                q1s[g] = (unsigned int)__shfl_xor((int)pk1[g], 32, 64);

            if (havePrev) {
#pragma unroll
                for (int s2 = 0; s2 < 4; ++s2)
                    acc0 = __builtin_amdgcn_mfma_f32_32x32x16_bf16(
                        __builtin_bit_cast(bf16x8, va0[s2]),
                        __builtin_bit_cast(bf16x8, pf[s2]), acc0, 0, 0, 0);
#pragma unroll
                for (int s2 = 0; s2 < 4; ++s2)
                    acc1 = __builtin_amdgcn_mfma_f32_32x32x16_bf16(
                        __builtin_bit_cast(bf16x8, va1[s2]),
                        __builtin_bit_cast(bf16x8, pf[s2]), acc1, 0, 0, 0);
            }

            {
                const unsigned short* vt = vbase + (size_t)T * 4096;
#pragma unroll
                for (int s2 = 0; s2 < 4; ++s2) {
                    va0[s2] = *(const uint4*)(vt + s2 * 1024);
                    va1[s2] = *(const uint4*)(vt + s2 * 1024 + 512);
                }
            }

#pragma unroll
            for (int s2 = 0; s2 < 2; ++s2) {
                const int ba = 4 * s2;
                pf[s2].x = h ? q0s[ba + 2] : pk0[ba];
                pf[s2].y = h ? q0s[ba + 3] : pk0[ba + 1];
                pf[s2].z = h ? pk0[ba + 2] : q0s[ba];
                pf[s2].w = h ? pk0[ba + 3] : q0s[ba + 1];
            }
#pragma unroll
            for (int s2 = 2; s2 < 4; ++s2) {
                const int ba = 4 * (s2 - 2);
                pf[s2].x = h ? q1s[ba + 2] : pk1[ba];
                pf[s2].y = h ? q1s[ba + 3] : pk1[ba + 1];
                pf[s2].z = h ? pk1[ba + 2] : q1s[ba];
                pf[s2].w = h ? pk1[ba + 3] : q1s[ba + 1];
            }
            havePrev = true;
        }
    }

#pragma unroll
    for (int s2 = 0; s2 < 4; ++s2)
        acc0 = __builtin_amdgcn_mfma_f32_32x32x16_bf16(
            __builtin_bit_cast(bf16x8, va0[s2]),
            __builtin_bit_cast(bf16x8, pf[s2]), acc0, 0, 0, 0);
#pragma unroll
    for (int s2 = 0; s2 < 4; ++s2)
        acc1 = __builtin_amdgcn_mfma_f32_32x32x16_bf16(
            __builtin_bit_cast(bf16x8, va1[s2]),
            __builtin_bit_cast(bf16x8, pf[s2]), acc1, 0, 0, 0);

    // ---- tree merge (plain sums, static m) ----
    l_sh[w * 64 + lane] = (sA + sB) + (sC + sD);
    float* mw = smem_f;
    auto wr = [&](int srcw) {
#pragma unroll
        for (int r4 = 0; r4 < 4; ++r4) {
            *(float4*)&mw[((size_t)(srcw * 2 + 0) * 64 + lane) * 16 + 4 * r4] =
                make_float4(acc0[4*r4], acc0[4*r4+1], acc0[4*r4+2], acc0[4*r4+3]);
            *(float4*)&mw[((size_t)(srcw * 2 + 1) * 64 + lane) * 16 + 4 * r4] =
                make_float4(acc1[4*r4], acc1[4*r4+1], acc1[4*r4+2], acc1[4*r4+3]);
        }
    };
    auto rd = [&](int srcw) {
#pragma unroll
        for (int r4 = 0; r4 < 4; ++r4) {
            float4 a = *(const float4*)&mw[((size_t)(srcw * 2 + 0) * 64 + lane) * 16 + 4 * r4];
            float4 c = *(const float4*)&mw[((size_t)(srcw * 2 + 1) * 64 + lane) * 16 + 4 * r4];
            acc0[4*r4]   += a.x; acc0[4*r4+1] += a.y; acc0[4*r4+2] += a.z; acc0[4*r4+3] += a.w;
            acc1[4*r4]   += c.x; acc1[4*r4+1] += c.y; acc1[4*r4+2] += c.z; acc1[4*r4+3] += c.w;
        }
    };
    if (w >= 4) wr(w - 4);
    __syncthreads();
    if (w < 4) rd(w);
    __syncthreads();
    if (w >= 2 && w < 4) wr(w - 2);
    __syncthreads();
    if (w < 2) rd(w);
    __syncthreads();
    if (w == 1) wr(0);
    __syncthreads();
    if (w == 0) {
        rd(0);
        float l_tot = 0.0f;
#pragma unroll
        for (int ww = 0; ww < 8; ++ww)
            l_tot += l_sh[ww * 64 + l31] + l_sh[ww * 64 + 32 + l31];
        const float inv = 1.0f / l_tot;
        const float g = gamma[0];
#pragma unroll
        for (int r = 0; r < 16; ++r) {
            int c = (r & 3) + 8 * (r >> 2) + 4 * h;
            size_t i0 = ((size_t)b * 64 + c) * NVOX + m0 + l31;
            size_t i1 = ((size_t)b * 64 + c + 32) * NVOX + m0 + l31;
            out[i0] = g * (acc0[r] * inv) + x[i0];
            out[i1] = g * (acc1[r] * inv) + x[i1];
        }
    }
}

// ---------------------------------------------------------------------------
extern "C" void kernel_launch(void* const* d_in, const int* in_sizes, int n_in,
                              void* d_out, int out_size, void* d_ws, size_t ws_size,
                              hipStream_t stream) {
    const float* x     = (const float*)d_in[0];
    const float* wq    = (const float*)d_in[1];
    const float* bq    = (const float*)d_in[2];
    const float* wk    = (const float*)d_in[3];
    const float* bk    = (const float*)d_in[4];
    const float* wv    = (const float*)d_in[5];
    const float* bv    = (const float*)d_in[6];
    const float* gamma = (const float*)d_in[7];
    float* out = (float*)d_out;

    unsigned short* qws = (unsigned short*)d_ws;            // [16000][16] hi|lo (log2e-scaled)
    unsigned short* kws = qws + (size_t)BATCH * NVOX * 16;  // [16000][8]
    unsigned short* vws = kws + (size_t)BATCH * NVOX * 8;   // [2][125][4][2][2][32][8] frag-linear

    qkv_kernel<<<500, 192, 0, stream>>>(x, wq, bq, wk, bk, wv, bv, qws, kws, vws);
    attn_kernel<<<BATCH * QTILES, 512, 0, stream>>>(qws, kws, vws, x, gamma, out);
}

// Round 13
// 113.869 us; speedup vs baseline: 2.9486x; 1.0502x over previous
//
#include <hip/hip_runtime.h>
#include <math.h>

#define BATCH  2
#define NVOX   8000
#define MT     32            // queries per attn block
#define KT     64            // keys per tile
#define NTILES 125
#define QTILES 250
#define LOG2E  1.44269504f
#define MSTAT  32.0f         // static softmax shift (log2 domain)

typedef float  f32x16 __attribute__((ext_vector_type(16)));
typedef __bf16 bf16x8 __attribute__((ext_vector_type(8)));
typedef unsigned short u16x8 __attribute__((ext_vector_type(8)));

__device__ __forceinline__ unsigned short f2bf(float f) {
    return __builtin_bit_cast(unsigned short, (__bf16)f);
}
// HW packed f32x2 -> bf16x2 (one VOP3 instead of ~8 VALU of software RNE)
__device__ __forceinline__ unsigned int packbf(float lo, float hi) {
    unsigned int r;
    asm("v_cvt_pk_bf16_f32 %0, %1, %2" : "=v"(r) : "v"(lo), "v"(hi));
    return r;
}
// schedulable native 2^x (no opaque asm block -> compiler can interleave)
__device__ __forceinline__ float fexp2(float x) {
    return __builtin_amdgcn_exp2f(x);
}

// V workspace layout (R8/R9, proven): fragment-linear
//   u16 index = (b*125+T)*4096 + s2*1024 + cg*512 + p*256 + c31*8 + j
//   holds V[c=cg*32+c31][key = T*64 + s2*16 + p*8 + j]

// ---------------------------------------------------------------------------
// Kernel 1: projection GEMM. 500 blocks x 192 thr, 32 distinct voxels/block.
// (R9 verbatim — proven; qkv is off the critical path.)
// ---------------------------------------------------------------------------
__global__ __launch_bounds__(192) void qkv_kernel(
    const float* __restrict__ x,
    const float* __restrict__ wq, const float* __restrict__ bq,
    const float* __restrict__ wk, const float* __restrict__ bk,
    const float* __restrict__ wv, const float* __restrict__ bv,
    unsigned short* __restrict__ qws, unsigned short* __restrict__ kws,
    unsigned short* __restrict__ vws)
{
    // st rows: 0-7 q-hi, 8-15 k, 16-79 v, 80-87 q-lo; cols = 32 voxels; stride 40
    __shared__ __align__(16) unsigned short st[88 * 40];
    const int t = threadIdx.x, lane = t & 63, ot = t >> 6;   // ot 0..2
    const int l31 = lane & 31, h = lane >> 5;
    const int blk = blockIdx.x, b = blk / 250, v0 = (blk % 250) * 32;
    const int n = v0 + l31;

    const int o = ot * 32 + l31;
    const float* wsrc;
    float scale = 1.0f;
    if (o < 8)       { wsrc = wq + o * 64; scale = LOG2E; }
    else if (o < 16) { wsrc = wk + (o - 8) * 64; }
    else             { wsrc = wv + ((o - 16) & 63) * 64; }   // o>=80: junk, never stored

    bf16x8 Ah[4], Al[4];
#pragma unroll
    for (int cc = 0; cc < 4; ++cc) {
        float4 w0 = *(const float4*)(wsrc + cc * 16 + 8 * h);
        float4 w1 = *(const float4*)(wsrc + cc * 16 + 8 * h + 4);
        float wf[8] = { w0.x, w0.y, w0.z, w0.w, w1.x, w1.y, w1.z, w1.w };
        unsigned short hh[8], ll[8];
#pragma unroll
        for (int j = 0; j < 8; ++j) {
            float wv_ = wf[j] * scale;
            __bf16 hb = (__bf16)wv_;
            hh[j] = __builtin_bit_cast(unsigned short, hb);
            ll[j] = f2bf(wv_ - (float)hb);
        }
        Ah[cc] = __builtin_bit_cast(bf16x8, *(u16x8*)hh);
        Al[cc] = __builtin_bit_cast(bf16x8, *(u16x8*)ll);
    }

    bf16x8 Bhi[4], Blo[4];
    const float* xb = x + (size_t)b * 64 * NVOX + n;
#pragma unroll
    for (int cc = 0; cc < 4; ++cc) {
        unsigned short bh[8], bl[8];
#pragma unroll
        for (int j = 0; j < 8; ++j) {
            float xf = xb[(size_t)(cc * 16 + 8 * h + j) * NVOX];
            __bf16 xh = (__bf16)xf;
            bh[j] = __builtin_bit_cast(unsigned short, xh);
            bl[j] = f2bf(xf - (float)xh);
        }
        Bhi[cc] = __builtin_bit_cast(bf16x8, *(u16x8*)bh);
        Blo[cc] = __builtin_bit_cast(bf16x8, *(u16x8*)bl);
    }

    f32x16 acc;
#pragma unroll
    for (int r = 0; r < 16; ++r) acc[r] = 0.0f;
#pragma unroll
    for (int cc = 0; cc < 4; ++cc) {
        acc = __builtin_amdgcn_mfma_f32_32x32x16_bf16(Ah[cc], Bhi[cc], acc, 0, 0, 0);
        acc = __builtin_amdgcn_mfma_f32_32x32x16_bf16(Al[cc], Bhi[cc], acc, 0, 0, 0);
        acc = __builtin_amdgcn_mfma_f32_32x32x16_bf16(Ah[cc], Blo[cc], acc, 0, 0, 0);
    }

#pragma unroll
    for (int r = 0; r < 16; ++r) {
        int oo = ot * 32 + (r & 3) + 8 * (r >> 2) + 4 * h;
        if (oo >= 80) continue;
        float bias = (oo < 8) ? bq[oo] * LOG2E : (oo < 16) ? bk[oo - 8] : bv[oo - 16];
        float v = acc[r] + bias;
        if (oo < 8) {
            __bf16 hb = (__bf16)v;
            st[oo * 40 + l31]        = __builtin_bit_cast(unsigned short, hb);
            st[(80 + oo) * 40 + l31] = f2bf(v - (float)hb);
        } else {
            st[oo * 40 + l31] = f2bf(v);
        }
    }
    __syncthreads();

    // ---- coalesced 16B stores ----
    for (int idx = t; idx < 256; idx += 192) {
        int ch = idx >> 2, q = idx & 3;
        int T = v0 >> 6;
        int off = (v0 & 63) + q * 8;
        int s2 = off >> 4, p = (off >> 3) & 1;
        int cg = ch >> 5, c31 = ch & 31;
        size_t dst = (size_t)(b * 125 + T) * 4096 + s2 * 1024 + cg * 512
                   + p * 256 + c31 * 8;
        *(uint4*)(vws + dst) = *(const uint4*)&st[(16 + ch) * 40 + q * 8];
    }
    if (t >= 128) {                      // qws: 32 vox x {hi,lo} = 64 units
        int i = t - 128, vox = i >> 1, half = i & 1;
        int rbase = half ? 80 : 0;
        unsigned short g[8];
#pragma unroll
        for (int r = 0; r < 8; ++r) g[r] = st[(rbase + r) * 40 + vox];
        *(uint4*)(qws + (size_t)(b * NVOX + v0 + vox) * 16 + half * 8) = *(uint4*)g;
    } else if (t >= 96) {                // kws: 32 vox
        int vox = t - 96;
        unsigned short g[8];
#pragma unroll
        for (int r = 0; r < 8; ++r) g[r] = st[(8 + r) * 40 + vox];
        *(uint4*)(kws + (size_t)(b * NVOX + v0 + vox) * 8) = *(uint4*)g;
    }
}

// ---------------------------------------------------------------------------
// Kernel 2: flash attention (R9 structure, proven). 500 blocks x 512 thr,
// wave w owns tiles T = w+8S. Pipelined by one tile. R13 delta: hardware
// v_cvt_pk_bf16_f32 for the P pack (1 op vs ~8) and builtin exp2 (schedulable).
// ---------------------------------------------------------------------------
__global__ __launch_bounds__(512, 1) void attn_kernel(
    const unsigned short* __restrict__ qws, const unsigned short* __restrict__ kws,
    const unsigned short* __restrict__ vws, const float* __restrict__ x,
    const float* __restrict__ gamma, float* __restrict__ out)
{
    __shared__ float smem_f[8704];          // 32KB merge + 2KB l
    float* l_sh = smem_f + 8192;            // [8][64]

    const int blk = blockIdx.x, b = blk / QTILES, m0 = (blk % QTILES) * MT;
    const int t = threadIdx.x, lane = t & 63, w = t >> 6;
    const int l31 = lane & 31, h = lane >> 5;

    // Q B-frag (log2e pre-folded): col=query l31, h=0 hi / h=1 lo
    const bf16x8 qf = __builtin_bit_cast(bf16x8,
        *(const u16x8*)(qws + (size_t)(b * NVOX + m0 + l31) * 16 + h * 8));

    const unsigned short* ksrc = kws + (size_t)b * NVOX * 8;
    const unsigned short* vbase = vws + (size_t)b * 512000 + h * 256 + l31 * 8;

    f32x16 acc0, acc1, zro;
#pragma unroll
    for (int r = 0; r < 16; ++r) { acc0[r] = 0.0f; acc1[r] = 0.0f; zro[r] = 0.0f; }
    float sA = 0.0f, sB = 0.0f, sC = 0.0f, sD = 0.0f;

    uint4 va0[4], va1[4];
    uint4 pf[4];
    bf16x8 kf0c = __builtin_bit_cast(bf16x8, *(const u16x8*)(ksrc + (size_t)(w * KT + l31) * 8));
    bf16x8 kf1c = __builtin_bit_cast(bf16x8, *(const u16x8*)(ksrc + (size_t)(w * KT + 32 + l31) * 8));
    bool havePrev = false;

#pragma unroll 1
    for (int S = 0; S < 16; ++S) {
        const int T = w + 8 * S;
        if (T < NTILES) {
            const int Tn = T + 8;

            bf16x8 kf0n = kf0c, kf1n = kf1c;
            if (Tn < NTILES) {
                const int nn = Tn * KT;
                kf0n = __builtin_bit_cast(bf16x8, *(const u16x8*)(ksrc + (size_t)(nn + l31) * 8));
                kf1n = __builtin_bit_cast(bf16x8, *(const u16x8*)(ksrc + (size_t)(nn + 32 + l31) * 8));
            }

            f32x16 E0 = __builtin_amdgcn_mfma_f32_32x32x16_bf16(kf0c, qf, zro, 0, 0, 0);
            f32x16 E1 = __builtin_amdgcn_mfma_f32_32x32x16_bf16(kf1c, qf, zro, 0, 0, 0);
            kf0c = kf0n; kf1c = kf1n;

            unsigned int pk0[8], q0s[8], pk1[8], q1s[8];
#pragma unroll
            for (int g = 0; g < 8; ++g) {
                float pa = fexp2(E0[2 * g] - MSTAT);
                float pb = fexp2(E0[2 * g + 1] - MSTAT);
                sA += pa; sB += pb;
                pk0[g] = packbf(pa, pb);
            }
#pragma unroll
            for (int g = 0; g < 8; ++g) {
                float pa = fexp2(E1[2 * g] - MSTAT);
                float pb = fexp2(E1[2 * g + 1] - MSTAT);
                sC += pa; sD += pb;
                pk1[g] = packbf(pa, pb);
            }
#pragma unroll
            for (int g = 0; g < 8; ++g)
                q0s[g] = (unsigned int)__shfl_xor((int)pk0[g], 32, 64);
#pragma unroll
            for (int g = 0; g < 8; ++g)
                q1s[g] = (unsigned int)__shfl_xor((int)pk1[g], 32, 64);

            if (havePrev) {
#pragma unroll
                for (int s2 = 0; s2 < 4; ++s2)
                    acc0 = __builtin_amdgcn_mfma_f32_32x32x16_bf16(
                        __builtin_bit_cast(bf16x8, va0[s2]),
                        __builtin_bit_cast(bf16x8, pf[s2]), acc0, 0, 0, 0);
#pragma unroll
                for (int s2 = 0; s2 < 4; ++s2)
                    acc1 = __builtin_amdgcn_mfma_f32_32x32x16_bf16(
                        __builtin_bit_cast(bf16x8, va1[s2]),
                        __builtin_bit_cast(bf16x8, pf[s2]), acc1, 0, 0, 0);
            }

            {
                const unsigned short* vt = vbase + (size_t)T * 4096;
#pragma unroll
                for (int s2 = 0; s2 < 4; ++s2) {
                    va0[s2] = *(const uint4*)(vt + s2 * 1024);
                    va1[s2] = *(const uint4*)(vt + s2 * 1024 + 512);
                }
            }

#pragma unroll
            for (int s2 = 0; s2 < 2; ++s2) {
                const int ba = 4 * s2;
                pf[s2].x = h ? q0s[ba + 2] : pk0[ba];
                pf[s2].y = h ? q0s[ba + 3] : pk0[ba + 1];
                pf[s2].z = h ? pk0[ba + 2] : q0s[ba];
                pf[s2].w = h ? pk0[ba + 3] : q0s[ba + 1];
            }
#pragma unroll
            for (int s2 = 2; s2 < 4; ++s2) {
                const int ba = 4 * (s2 - 2);
                pf[s2].x = h ? q1s[ba + 2] : pk1[ba];
                pf[s2].y = h ? q1s[ba + 3] : pk1[ba + 1];
                pf[s2].z = h ? pk1[ba + 2] : q1s[ba];
                pf[s2].w = h ? pk1[ba + 3] : q1s[ba + 1];
            }
            havePrev = true;
        }
    }

    // ---- drain: PV for the last tile
#pragma unroll
    for (int s2 = 0; s2 < 4; ++s2)
        acc0 = __builtin_amdgcn_mfma_f32_32x32x16_bf16(
            __builtin_bit_cast(bf16x8, va0[s2]),
            __builtin_bit_cast(bf16x8, pf[s2]), acc0, 0, 0, 0);
#pragma unroll
    for (int s2 = 0; s2 < 4; ++s2)
        acc1 = __builtin_amdgcn_mfma_f32_32x32x16_bf16(
            __builtin_bit_cast(bf16x8, va1[s2]),
            __builtin_bit_cast(bf16x8, pf[s2]), acc1, 0, 0, 0);

    // ---- tree merge (plain sums, static m) ----
    l_sh[w * 64 + lane] = (sA + sB) + (sC + sD);
    float* mw = smem_f;
    auto wr = [&](int srcw) {
#pragma unroll
        for (int r4 = 0; r4 < 4; ++r4) {
            *(float4*)&mw[((size_t)(srcw * 2 + 0) * 64 + lane) * 16 + 4 * r4] =
                make_float4(acc0[4*r4], acc0[4*r4+1], acc0[4*r4+2], acc0[4*r4+3]);
            *(float4*)&mw[((size_t)(srcw * 2 + 1) * 64 + lane) * 16 + 4 * r4] =
                make_float4(acc1[4*r4], acc1[4*r4+1], acc1[4*r4+2], acc1[4*r4+3]);
        }
    };
    auto rd = [&](int srcw) {
#pragma unroll
        for (int r4 = 0; r4 < 4; ++r4) {
            float4 a = *(const float4*)&mw[((size_t)(srcw * 2 + 0) * 64 + lane) * 16 + 4 * r4];
            float4 c = *(const float4*)&mw[((size_t)(srcw * 2 + 1) * 64 + lane) * 16 + 4 * r4];
            acc0[4*r4]   += a.x; acc0[4*r4+1] += a.y; acc0[4*r4+2] += a.z; acc0[4*r4+3] += a.w;
            acc1[4*r4]   += c.x; acc1[4*r4+1] += c.y; acc1[4*r4+2] += c.z; acc1[4*r4+3] += c.w;
        }
    };
    if (w >= 4) wr(w - 4);
    __syncthreads();
    if (w < 4) rd(w);
    __syncthreads();
    if (w >= 2 && w < 4) wr(w - 2);
    __syncthreads();
    if (w < 2) rd(w);
    __syncthreads();
    if (w == 1) wr(0);
    __syncthreads();
    if (w == 0) {
        rd(0);
        float l_tot = 0.0f;
#pragma unroll
        for (int ww = 0; ww < 8; ++ww)
            l_tot += l_sh[ww * 64 + l31] + l_sh[ww * 64 + 32 + l31];
        const float inv = 1.0f / l_tot;
        const float g = gamma[0];
#pragma unroll
        for (int r = 0; r < 16; ++r) {
            int c = (r & 3) + 8 * (r >> 2) + 4 * h;
            size_t i0 = ((size_t)b * 64 + c) * NVOX + m0 + l31;
            size_t i1 = ((size_t)b * 64 + c + 32) * NVOX + m0 + l31;
            out[i0] = g * (acc0[r] * inv) + x[i0];
            out[i1] = g * (acc1[r] * inv) + x[i1];
        }
    }
}

// ---------------------------------------------------------------------------
extern "C" void kernel_launch(void* const* d_in, const int* in_sizes, int n_in,
                              void* d_out, int out_size, void* d_ws, size_t ws_size,
                              hipStream_t stream) {
    const float* x     = (const float*)d_in[0];
    const float* wq    = (const float*)d_in[1];
    const float* bq    = (const float*)d_in[2];
    const float* wk    = (const float*)d_in[3];
    const float* bk    = (const float*)d_in[4];
    const float* wv    = (const float*)d_in[5];
    const float* bv    = (const float*)d_in[6];
    const float* gamma = (const float*)d_in[7];
    float* out = (float*)d_out;

    unsigned short* qws = (unsigned short*)d_ws;            // [16000][16] hi|lo (log2e-scaled)
    unsigned short* kws = qws + (size_t)BATCH * NVOX * 16;  // [16000][8]
    unsigned short* vws = kws + (size_t)BATCH * NVOX * 8;   // [2][125][4][2][2][32][8] frag-linear

    qkv_kernel<<<500, 192, 0, stream>>>(x, wq, bq, wk, bk, wv, bv, qws, kws, vws);
    attn_kernel<<<BATCH * QTILES, 512, 0, stream>>>(qws, kws, vws, x, gamma, out);
}